// Round 3
// baseline (1220.737 us; speedup 1.0000x reference)
//
#include <hip/hip_runtime.h>
#include <hip/hip_bf16.h>
#include <stdint.h>

// SJ_SNN: bit-exact replica of the golden (jax on CPU -> XLA/Eigen fp32):
// per output element the contraction is a SINGLE accumulator, ascending k,
// true FMA. PASS r6/r7/r9/r10 (absmax 0.00390625 = golden bf16 floor).
// r11: GEMM rearchitected to kill the LDS operand path (r10 was LDS-return-
// path bound: 4x ds_read_b128 per k per wave = 192 LDS cyc/CU vs 128 FMA
// cyc/SIMD; model 348us ~= measured 408us):
//  - wave tile 256m x 16n: B fragment is WAVE-UNIFORM -> s_load_dwordx16
//    from pre-transposed W0T[k][e] into SGPRs (v_fmac_f32 v,s,v). No LDS.
//  - x pre-transposed to xT[k][m] (exact copy): A fragment = one coalesced
//    global_load_dwordx4 per lane per k, L1-served (4 waves share m-stripe).
//  - NO __syncthreads in the main loop; LDS used only for the coalesced
//    C epilogue (2 rounds of 128x64, full-line stores - r10 lesson: partial-
//    line global stores cause L2 RMW; r9 WRITE_SIZE 4.3x disaster).

__global__ void k_zero(unsigned int* __restrict__ p, int n){
  int i = blockIdx.x * 256 + threadIdx.x;
  if (i < n) p[i] = 0u;
}

// out[C][R] = in[R][C]  (exact fp32 copy)
__global__ void k_transpose(const float* __restrict__ in, float* __restrict__ out, int R, int C){
  __shared__ float tile[32][33];
  int bx = blockIdx.x * 32, by = blockIdx.y * 32;
  int tx = threadIdx.x, ty = threadIdx.y;
  for (int i = ty; i < 32; i += 8)
    tile[i][tx] = in[(size_t)(by + i) * C + bx + tx];
  __syncthreads();
  for (int i = ty; i < 32; i += 8)
    out[(size_t)(bx + i) * R + by + tx] = tile[tx][i];
}

__device__ __forceinline__ void fma16x4(const float4& a, const float* b, float acc[4][16]){
#pragma unroll
  for (int j = 0; j < 4; ++j){
    const float av = j == 0 ? a.x : (j == 1 ? a.y : (j == 2 ? a.z : a.w));
#pragma unroll
    for (int i = 0; i < 16; ++i)
      acc[j][i] = __fmaf_rn(av, b[i], acc[j][i]);
  }
}

// Layer-0 GEMM, Eigen order: C[m][e] = (single ascending FMA chain over
// k=0..511 of xT[k][m]*W0T[k][e]) + bias[e].
// Block: 256 threads = 4 waves; tile 256m x 64n; wave w owns e-slice
// [bn+16w, bn+16w+16) (wave-uniform -> SGPR B); lane owns m rows
// bm + lane*4 .. +3 (contiguous -> coalesced dwordx4 A loads).
// Grid: x = n-tile (fast) so co-resident blocks share the xT m-stripe in L2.
__global__ __launch_bounds__(256, 4) void k_gemm_sm(const float* __restrict__ xT,
    const float* __restrict__ W0T, const float* __restrict__ bias,
    float* __restrict__ C, int M){
  __shared__ float S[128 * 68];
  const int tid  = threadIdx.x;
  const int lane = tid & 63;
  const int w    = tid >> 6;
  const int bn   = blockIdx.x * 64;
  const int bm   = blockIdx.y * 256;
  int e0 = __builtin_amdgcn_readfirstlane(bn + w * 16);
  const float* __restrict__ Arow = xT + bm + lane * 4;
  const float* __restrict__ Wrow = W0T + e0;

  float acc[4][16];
#pragma unroll
  for (int j = 0; j < 4; ++j)
#pragma unroll
    for (int i = 0; i < 16; ++i) acc[j][i] = 0.f;

  // 2-stage software pipeline; b values are uniform -> SGPRs via s_load.
  float4 aA = *(const float4*)(Arow);
  float bA[16], bB[16];
#pragma unroll
  for (int i = 0; i < 16; ++i) bA[i] = Wrow[i];

  for (int k = 0; k < 512; k += 2){
    float4 aB = *(const float4*)(Arow + (size_t)(k + 1) * M);
#pragma unroll
    for (int i = 0; i < 16; ++i) bB[i] = Wrow[(k + 1) * 1024 + i];
    fma16x4(aA, bA, acc);
    if (k + 2 < 512){
      aA = *(const float4*)(Arow + (size_t)(k + 2) * M);
#pragma unroll
      for (int i = 0; i < 16; ++i) bA[i] = Wrow[(k + 2) * 1024 + i];
    }
    fma16x4(aB, bB, acc);
  }

  // bias (wave-uniform), then LDS-staged coalesced epilogue.
#pragma unroll
  for (int i = 0; i < 16; ++i){
    const float bi = bias[e0 + i];
#pragma unroll
    for (int j = 0; j < 4; ++j) acc[j][i] = __fadd_rn(acc[j][i], bi);
  }

#pragma unroll
  for (int t = 0; t < 2; ++t){
    if (t) __syncthreads();              // round-0 reads done before overwrite
    if ((lane >> 5) == t){
      const int lm4 = (lane & 31) * 4;   // row within this 128-row half
#pragma unroll
      for (int j = 0; j < 4; ++j)
#pragma unroll
        for (int i4 = 0; i4 < 4; ++i4)
          *(float4*)&S[(lm4 + j) * 68 + (w * 16 + i4 * 4)] =
            make_float4(acc[j][i4 * 4 + 0], acc[j][i4 * 4 + 1],
                        acc[j][i4 * 4 + 2], acc[j][i4 * 4 + 3]);
    }
    __syncthreads();
#pragma unroll
    for (int u = 0; u < 8; ++u){
      int idx = u * 256 + tid;
      int row = idx >> 4;
      int c4  = (idx & 15) << 2;
      float4 v = *(const float4*)&S[row * 68 + c4];
      *(float4*)&C[(size_t)(bm + t * 128 + row) * 1024 + (bn + c4)] = v;
    }
  }
}

// BN stats: per (chunk, channel), SEQUENTIAL in-order over 256 samples.
__global__ __launch_bounds__(256) void k_stats_np(const float* __restrict__ A,
    float* __restrict__ mu, float* __restrict__ var, int Dch, int c0){
  int cl = blockIdx.x;
  int ch = blockIdx.y * 256 + threadIdx.x;
  const float* base = A + (size_t)cl * 256 * Dch + ch;
  float acc = 0.f;
  for (int s = 0; s < 256; ++s)
    acc = __fadd_rn(acc, base[(size_t)s * Dch]);
  float m = __fmul_rn(acc, 1.f / 256.f);   // /256 exact (pow2)
  float vacc = 0.f;
  for (int s = 0; s < 256; ++s){
    float d = __fsub_rn(base[(size_t)s * Dch], m);
    vacc = __fadd_rn(vacc, __fmul_rn(d, d));
  }
  int c = c0 + cl;
  mu[(size_t)c * Dch + ch]  = m;
  var[(size_t)c * Dch + ch] = __fmul_rn(vacc, 1.f / 256.f);
}

// fp32 BN + LIF scan (hidden layers): spike bitmasks, 64-thread blocks,
// software-pipelined chunk prefetch (8 independent loads in flight).
__global__ __launch_bounds__(64) void k_scan_spike_np(const float* __restrict__ A,
    const float* __restrict__ mu, const float* __restrict__ var,
    const float* __restrict__ g, const float* __restrict__ bt,
    float* __restrict__ vstate, unsigned long long* __restrict__ mask,
    int Dch, int c0, int nb){
  int ebn = Dch >> 6;
  int eb = blockIdx.x % ebn;
  int b  = blockIdx.x / ebn;
  int e  = (eb << 6) + threadIdx.x;
  float gg = g[e], bb = bt[e];
  float v = vstate[(size_t)b * Dch + e];
  float hbuf[8];
#pragma unroll
  for (int t = 0; t < 8; ++t)
    hbuf[t] = A[(size_t)(t * 32 + b) * Dch + e];
  for (int cl = 0; cl < nb; ++cl){
    int c = c0 + cl;
    float m  = mu[(size_t)c * Dch + e];
    float ve = __fadd_rn(var[(size_t)c * Dch + e], 1e-5f);
    float sq = (float)sqrt((double)ve);          // correctly-rounded fp32 sqrt
    float r  = (float)(1.0 / (double)sq);        // correctly-rounded fp32 div
    float hn[8];
    if (cl + 1 < nb){
#pragma unroll
      for (int t = 0; t < 8; ++t)
        hn[t] = A[(size_t)(((cl + 1) * 8 + t) * 32 + b) * Dch + e];
    } else {
#pragma unroll
      for (int t = 0; t < 8; ++t) hn[t] = 0.f;
    }
#pragma unroll
    for (int t = 0; t < 8; ++t){
      int sl = (cl * 8 + t) * 32 + b;
      float xn = __fadd_rn(__fmul_rn(__fmul_rn(gg, __fsub_rn(hbuf[t], m)), r), bb);
      v = __fadd_rn(v, __fmul_rn(__fsub_rn(xn, v), 0.5f));
      bool sp = (v >= 1.0f);                     // == (v-1>=0)
      unsigned long long bal = __ballot(sp);
      if (sp) v = 0.0f;
      if (threadIdx.x == 0) mask[(size_t)sl * 16 + eb] = bal;
    }
#pragma unroll
    for (int t = 0; t < 8; ++t) hbuf[t] = hn[t];
  }
  vstate[(size_t)b * Dch + e] = v;
}

// Sparse spike linear, Eigen order: thread 0 of each sample-slot extracts the
// ascending spike list into LDS; waves consume with 4 loads in flight.
// Single-accumulator ascending add chain preserved exactly.
__global__ __launch_bounds__(256) void k_sparse_np(const unsigned long long* __restrict__ mask,
    const float* __restrict__ WT, const float* __restrict__ bias,
    float* __restrict__ C, int Dout){
  int tid = threadIdx.x;
  int lane = tid & 63;
  int wid = tid >> 6;
  int wps = Dout >> 8;            // waves per sample: 4 (1024) or 2 (512)
  int chgrp = wid % wps;
  int sgrp  = wid / wps;
  int spb   = 4 / wps;            // samples per block
  int s = blockIdx.x * spb + sgrp;
  int ch = (chgrp << 8) + (lane << 2);
  __shared__ unsigned short list[2][1024];
  __shared__ int nlist[2];

  if (lane == 0 && chgrp == 0){
    const unsigned long long* mrow = mask + (size_t)s * 16;
    int n = 0;
    for (int w = 0; w < 16; ++w){
      unsigned long long msk = mrow[w];
      while (msk){
        int bit = __ffsll((unsigned long long)msk) - 1;
        msk &= msk - 1;
        list[sgrp][n++] = (unsigned short)(w * 64 + bit);
      }
    }
    nlist[sgrp] = n;
  }
  __syncthreads();
  int n = nlist[sgrp];
  const unsigned short* il = list[sgrp];
  float a0 = 0.f, a1 = 0.f, a2 = 0.f, a3 = 0.f;
  int i = 0;
  for (; i + 4 <= n; i += 4){
    int d0 = il[i], d1 = il[i + 1], d2 = il[i + 2], d3 = il[i + 3];
    float4 w0 = *(const float4*)(WT + (size_t)d0 * Dout + ch);
    float4 w1 = *(const float4*)(WT + (size_t)d1 * Dout + ch);
    float4 w2 = *(const float4*)(WT + (size_t)d2 * Dout + ch);
    float4 w3 = *(const float4*)(WT + (size_t)d3 * Dout + ch);
    a0 = __fadd_rn(a0, w0.x); a1 = __fadd_rn(a1, w0.y); a2 = __fadd_rn(a2, w0.z); a3 = __fadd_rn(a3, w0.w);
    a0 = __fadd_rn(a0, w1.x); a1 = __fadd_rn(a1, w1.y); a2 = __fadd_rn(a2, w1.z); a3 = __fadd_rn(a3, w1.w);
    a0 = __fadd_rn(a0, w2.x); a1 = __fadd_rn(a1, w2.y); a2 = __fadd_rn(a2, w2.z); a3 = __fadd_rn(a3, w2.w);
    a0 = __fadd_rn(a0, w3.x); a1 = __fadd_rn(a1, w3.y); a2 = __fadd_rn(a2, w3.z); a3 = __fadd_rn(a3, w3.w);
  }
  for (; i < n; ++i){
    int d = il[i];
    float4 wv = *(const float4*)(WT + (size_t)d * Dout + ch);
    a0 = __fadd_rn(a0, wv.x); a1 = __fadd_rn(a1, wv.y); a2 = __fadd_rn(a2, wv.z); a3 = __fadd_rn(a3, wv.w);
  }
  float4 bb = *(const float4*)(bias + ch);
  float4 o;
  o.x = __fadd_rn(a0, bb.x);
  o.y = __fadd_rn(a1, bb.y);
  o.z = __fadd_rn(a2, bb.z);
  o.w = __fadd_rn(a3, bb.w);
  *(float4*)(C + (size_t)s * Dout + ch) = o;
}

// Last layer: fp32 leaky integrator; sequential mean over 8 timesteps,
// /8 exact; float32 out. 64-thread blocks + chunk prefetch.
__global__ __launch_bounds__(64) void k_scan_last_np(const float* __restrict__ A,
    const float* __restrict__ mu, const float* __restrict__ var,
    const float* __restrict__ g, const float* __restrict__ bt,
    float* __restrict__ vstate, float* __restrict__ out, int c0, int nb){
  const int Dch = 512;
  int eb = blockIdx.x & 7;
  int b  = blockIdx.x >> 3;
  int e  = (eb << 6) + threadIdx.x;
  float gg = g[e], bb = bt[e];
  float v = vstate[(size_t)b * Dch + e];
  float hbuf[8];
#pragma unroll
  for (int t = 0; t < 8; ++t)
    hbuf[t] = A[(size_t)(t * 32 + b) * Dch + e];
  for (int cl = 0; cl < nb; ++cl){
    int c = c0 + cl;
    float m  = mu[(size_t)c * Dch + e];
    float ve = __fadd_rn(var[(size_t)c * Dch + e], 1e-5f);
    float sq = (float)sqrt((double)ve);
    float r  = (float)(1.0 / (double)sq);
    float hn[8];
    if (cl + 1 < nb){
#pragma unroll
      for (int t = 0; t < 8; ++t)
        hn[t] = A[(size_t)(((cl + 1) * 8 + t) * 32 + b) * Dch + e];
    } else {
#pragma unroll
      for (int t = 0; t < 8; ++t) hn[t] = 0.f;
    }
    float macc = 0.f;
#pragma unroll
    for (int t = 0; t < 8; ++t){
      float xn = __fadd_rn(__fmul_rn(__fmul_rn(gg, __fsub_rn(hbuf[t], m)), r), bb);
      v = __fadd_rn(v, __fmul_rn(__fsub_rn(xn, v), 0.5f));
      macc = __fadd_rn(macc, v);
    }
    out[((size_t)c * 32 + b) * 512 + e] = __fmul_rn(macc, 0.125f);
#pragma unroll
    for (int t = 0; t < 8; ++t) hbuf[t] = hn[t];
  }
  vstate[(size_t)b * Dch + e] = v;
}

static inline size_t al256(size_t x){ return (x + 255) & ~(size_t)255; }

extern "C" void kernel_launch(void* const* d_in, const int* in_sizes, int n_in,
                              void* d_out, int out_size, void* d_ws, size_t ws_size,
                              hipStream_t stream){
  (void)in_sizes; (void)n_in; (void)out_size;
  const float* x   = (const float*)d_in[0];
  const float* W0  = (const float*)d_in[1];
  const float* b0  = (const float*)d_in[2];
  const float* g0  = (const float*)d_in[3];
  const float* bt0 = (const float*)d_in[4];
  const float* W1  = (const float*)d_in[5];
  const float* b1  = (const float*)d_in[6];
  const float* g1  = (const float*)d_in[7];
  const float* bt1 = (const float*)d_in[8];
  const float* W2  = (const float*)d_in[9];
  const float* b2  = (const float*)d_in[10];
  const float* g2  = (const float*)d_in[11];
  const float* bt2 = (const float*)d_in[12];
  float* out = (float*)d_out;   // reference output dtype: float32

  char* p = (char*)d_ws;
  auto carve = [&](size_t bytes)->char*{ char* q = p; p += al256(bytes); return q; };
  float* W0T  = (float*)carve((size_t)512 * 1024 * 4);    // [k=512][e=1024]
  float* W1T  = (float*)carve((size_t)1024 * 1024 * 4);   // [d=1024][e=1024]
  float* W2T  = (float*)carve((size_t)1024 * 512 * 4);    // [d=1024][e=512]
  float* mu0  = (float*)carve((size_t)128 * 1024 * 4);
  float* var0 = (float*)carve((size_t)128 * 1024 * 4);
  float* mu1  = (float*)carve((size_t)128 * 1024 * 4);
  float* var1 = (float*)carve((size_t)128 * 1024 * 4);
  float* mu2  = (float*)carve((size_t)128 * 512 * 4);
  float* var2 = (float*)carve((size_t)128 * 512 * 4);
  float* v0   = (float*)carve((size_t)32 * 1024 * 4);
  float* v1   = (float*)carve((size_t)32 * 1024 * 4);
  float* v2   = (float*)carve((size_t)32 * 512 * 4);
  size_t fixed_used = (size_t)(p - (char*)d_ws);

  auto need = [&](int nb)->size_t{
    return al256((size_t)nb * 256 * 1024 * 4)        // fp32 activation buffer
         + al256((size_t)nb * 256 * 512 * 4)         // xT [512][nb*256]
         + 2 * al256((size_t)nb * 256 * 16 * 8);     // mask0, mask1
  };
  int NB = 128;
  while (NB > 1 && fixed_used + need(NB) > ws_size) NB >>= 1;
  if (fixed_used + need(NB) > ws_size) return;

  float*              a_buf = (float*)carve((size_t)NB * 256 * 1024 * 4);
  float*              xT    = (float*)carve((size_t)NB * 256 * 512 * 4);
  unsigned long long* mask0 = (unsigned long long*)carve((size_t)NB * 256 * 16 * 8);
  unsigned long long* mask1 = (unsigned long long*)carve((size_t)NB * 256 * 16 * 8);

  // zero v-states (carved contiguously: 32*(1024+1024+512) floats)
  {
    int nz = 32 * (1024 + 1024 + 512);
    k_zero<<<dim3((nz + 255) / 256), dim3(256), 0, stream>>>((unsigned int*)v0, nz);
  }
  k_transpose<<<dim3(16, 32), dim3(32, 8), 0, stream>>>(W0, W0T, 1024, 512);
  k_transpose<<<dim3(32, 32), dim3(32, 8), 0, stream>>>(W1, W1T, 1024, 1024);
  k_transpose<<<dim3(32, 16), dim3(32, 8), 0, stream>>>(W2, W2T, 512, 1024);

  int nblk = 128 / NB;
  for (int cb = 0; cb < nblk; ++cb){
    int c0 = cb * NB;
    int M = NB * 256;
    const float* xblk = x + (size_t)c0 * 256 * 512;

    // Layer 0: transpose x block (exact copy), then SGPR-B GEMM.
    k_transpose<<<dim3(16, M / 32), dim3(32, 8), 0, stream>>>(xblk, xT, M, 512);
    k_gemm_sm<<<dim3(16, M / 256), dim3(256), 0, stream>>>(xT, W0T, b0, a_buf, M);
    k_stats_np<<<dim3(NB, 4), dim3(256), 0, stream>>>(a_buf, mu0, var0, 1024, c0);
    k_scan_spike_np<<<dim3(32 * 16), dim3(64), 0, stream>>>(a_buf, mu0, var0, g0, bt0, v0, mask0, 1024, c0, NB);

    // Layer 1 (sparse, ascending single-chain, batched loads)
    k_sparse_np<<<dim3(M), dim3(256), 0, stream>>>(mask0, W1T, b1, a_buf, 1024);
    k_stats_np<<<dim3(NB, 4), dim3(256), 0, stream>>>(a_buf, mu1, var1, 1024, c0);
    k_scan_spike_np<<<dim3(32 * 16), dim3(64), 0, stream>>>(a_buf, mu1, var1, g1, bt1, v1, mask1, 1024, c0, NB);

    // Layer 2 (sparse) + integrator output
    k_sparse_np<<<dim3(M / 2), dim3(256), 0, stream>>>(mask1, W2T, b2, a_buf, 512);
    k_stats_np<<<dim3(NB, 2), dim3(256), 0, stream>>>(a_buf, mu2, var2, 512, c0);
    k_scan_last_np<<<dim3(32 * 8), dim3(64), 0, stream>>>(a_buf, mu2, var2, g2, bt2, v2, out, c0, NB);
  }
}

// Round 4
// 1107.465 us; speedup vs baseline: 1.1023x; 1.1023x over previous
//
#include <hip/hip_runtime.h>
#include <hip/hip_bf16.h>
#include <stdint.h>

// SJ_SNN: bit-exact replica of the golden (jax on CPU -> XLA/Eigen fp32):
// per output element the contraction is a SINGLE accumulator, ascending k,
// true FMA. PASS r6/r7/r9/r10/r11 (absmax 0.00390625 = golden bf16 floor).
// r12 = r10 GEMM restored (r11 SGPR-B regressed: 4 waves/block re-load the
// same A rows -> ~96 B/cyc L1 demand > ~64 B/cyc port; 431us vs 408us; also
// +42us x-transpose. r10's LDS path w/ b128 swizzle = best measured 408us)
// + sparse upgrades:
//  (a) wave-cooperative spike-list extraction: 16 lanes popcount their mask
//      word, __shfl prefix-scan, parallel ascending writes (~60 cyc vs
//      ~1000 serial on thread 0). List stays ascending -> chain bit-exact.
//  (b) weight-row pipeline deepened 4 -> 8 rows in flight.

__global__ void k_zero(unsigned int* __restrict__ p, int n){
  int i = blockIdx.x * 256 + threadIdx.x;
  if (i < n) p[i] = 0u;
}

// out[C][R] = in[R][C]  (exact fp32 copy)
__global__ void k_transpose(const float* __restrict__ in, float* __restrict__ out, int R, int C){
  __shared__ float tile[32][33];
  int bx = blockIdx.x * 32, by = blockIdx.y * 32;
  int tx = threadIdx.x, ty = threadIdx.y;
  for (int i = ty; i < 32; i += 8)
    tile[i][tx] = in[(size_t)(by + i) * C + bx + tx];
  __syncthreads();
  for (int i = ty; i < 32; i += 8)
    out[(size_t)(bx + i) * R + by + tx] = tile[tx][i];
}

// Layer-0 GEMM, Eigen order: C[m][e] = (single ascending FMA chain over
// k=0..511 of x[m][k]*W0[e][k]) + bias[e].
// 128(m) x 128(n) block tile, 8x8 per thread, 256 threads.
// Lane remap: c = tid bits {0,1,2,6}, r = tid bits {3,4,5,7} -> each wave is
// an 8x8 (r,c) square => per-wave fragment reads have 8 distinct addrs
// (8-lane broadcast groups).
// LDS layout: [32 k][132 floats]; slot(k,col) = G(k,col)*4 + (col&3) with
// G = (col>>2) ^ (col>>5) ^ (k>>3). Identity: slot(k, col4+j) = slot(k,col4)+j
// for 4-aligned col4, j<4, and slot(k, col+4) = slot(k, col) ^ 4.
__global__ __launch_bounds__(256, 3) void k_gemm_np(const float* __restrict__ A,
    const float* __restrict__ Bw, const float* __restrict__ bias,
    float* __restrict__ C, int M){
  (void)M;
  __shared__ float As[32][132];
  __shared__ float Bs[32][132];
  int bm = blockIdx.y * 128;
  int bn = blockIdx.x * 128;
  int tid = threadIdx.x;
  int kk = tid & 31, q = tid >> 5;                 // staging decode (q 0..7)
  int c = (tid & 7) | ((tid & 64) >> 3);           // 0..15
  int r = ((tid >> 3) & 7) | ((tid & 128) >> 4);   // 0..15
  int giA = (2 * r) ^ (r >> 2);                    // G(k=0, col=r*8)
  int giB = (2 * c) ^ (c >> 2);                    // G(k=0, col=c*8)
  float acc[8][8];
#pragma unroll
  for (int ii = 0; ii < 8; ++ii)
#pragma unroll
    for (int jj = 0; jj < 8; ++jj) acc[ii][jj] = 0.f;

  for (int k0 = 0; k0 < 512; k0 += 32){
    // stage: each thread builds 4-float column groups, one b128 write each.
    // global side: per (rr,j) instruction, lanes kk=0..31 are consecutive
    // addresses (128B segments).
#pragma unroll
    for (int rr = 0; rr < 4; ++rr){
      int colb = q * 4 + rr * 32;                  // 4-aligned, 0..124
      int gi = (colb >> 2) ^ (colb >> 5) ^ (kk >> 3);
      float4 va, vb;
      va.x = A[(size_t)(bm + colb + 0) * 512 + k0 + kk];
      va.y = A[(size_t)(bm + colb + 1) * 512 + k0 + kk];
      va.z = A[(size_t)(bm + colb + 2) * 512 + k0 + kk];
      va.w = A[(size_t)(bm + colb + 3) * 512 + k0 + kk];
      vb.x = Bw[(size_t)(bn + colb + 0) * 512 + k0 + kk];
      vb.y = Bw[(size_t)(bn + colb + 1) * 512 + k0 + kk];
      vb.z = Bw[(size_t)(bn + colb + 2) * 512 + k0 + kk];
      vb.w = Bw[(size_t)(bn + colb + 3) * 512 + k0 + kk];
      *(float4*)&As[kk][gi << 2] = va;
      *(float4*)&Bs[kk][gi << 2] = vb;
    }
    __syncthreads();
    // compute: ascending k overall (kg outer ascending, k8 inner ascending)
#pragma unroll
    for (int kg = 0; kg < 4; ++kg){
      const int sa = (giA ^ kg) << 2;
      const int sb = (giB ^ kg) << 2;
#pragma unroll
      for (int k8 = 0; k8 < 8; ++k8){
        const int k = kg * 8 + k8;
        float4 av0 = *(const float4*)&As[k][sa];
        float4 av1 = *(const float4*)&As[k][sa ^ 4];
        float4 bv0 = *(const float4*)&Bs[k][sb];
        float4 bv1 = *(const float4*)&Bs[k][sb ^ 4];
        float a[8] = {av0.x, av0.y, av0.z, av0.w, av1.x, av1.y, av1.z, av1.w};
        float b[8] = {bv0.x, bv0.y, bv0.z, bv0.w, bv1.x, bv1.y, bv1.z, bv1.w};
#pragma unroll
        for (int ii = 0; ii < 8; ++ii)
#pragma unroll
          for (int jj = 0; jj < 8; ++jj)
            acc[ii][jj] = __fmaf_rn(a[ii], b[jj], acc[ii][jj]);
      }
    }
    __syncthreads();
  }

  // Epilogue: bias + stage C tile through LDS (reusing As: exactly 32x132)
  // for fully-coalesced stores. 4 rounds, each 32 rows (ii pair) x 128 cols.
  float* S = &As[0][0];
  float4 bi0 = *(const float4*)(bias + bn + c * 8);
  float4 bi1 = *(const float4*)(bias + bn + c * 8 + 4);
  int rrow = tid >> 3;          // 0..31  (reader row in chunk)
  int f    = tid & 7;           // 0..7   (reader 16B-chunk within row)
  size_t mr = (size_t)(bm + (rrow >> 1) * 8 + (rrow & 1));  // + t4*2 below
#pragma unroll
  for (int t4 = 0; t4 < 4; ++t4){
    // write phase: rows 2r+p hold global rows bm + r*8 + (t4*2+p)
#pragma unroll
    for (int p = 0; p < 2; ++p){
      const int ii = t4 * 2 + p;
      const int row = r * 2 + p;
      const int giW = (2 * c) ^ (c >> 2) ^ (row >> 3);
      float4 o0, o1;
      o0.x = __fadd_rn(acc[ii][0], bi0.x);
      o0.y = __fadd_rn(acc[ii][1], bi0.y);
      o0.z = __fadd_rn(acc[ii][2], bi0.z);
      o0.w = __fadd_rn(acc[ii][3], bi0.w);
      o1.x = __fadd_rn(acc[ii][4], bi1.x);
      o1.y = __fadd_rn(acc[ii][5], bi1.y);
      o1.z = __fadd_rn(acc[ii][6], bi1.z);
      o1.w = __fadd_rn(acc[ii][7], bi1.w);
      *(float4*)&S[row * 132 + (giW << 2)] = o0;
      *(float4*)&S[row * 132 + ((giW << 2) ^ 4)] = o1;
    }
    __syncthreads();
    // read phase: per instruction a wave covers 8 rows x 128B contiguous.
#pragma unroll
    for (int u = 0; u < 4; ++u){
      int col4 = 4 * f + 32 * u;
      int giR = (f + 8 * u) ^ u ^ (rrow >> 3);
      float4 v = *(const float4*)&S[rrow * 132 + (giR << 2)];
      *(float4*)&C[(mr + (size_t)t4 * 2) * 1024 + bn + col4] = v;
    }
    __syncthreads();
  }
}

// BN stats: per (chunk, channel), SEQUENTIAL in-order over 256 samples.
__global__ __launch_bounds__(256) void k_stats_np(const float* __restrict__ A,
    float* __restrict__ mu, float* __restrict__ var, int Dch, int c0){
  int cl = blockIdx.x;
  int ch = blockIdx.y * 256 + threadIdx.x;
  const float* base = A + (size_t)cl * 256 * Dch + ch;
  float acc = 0.f;
  for (int s = 0; s < 256; ++s)
    acc = __fadd_rn(acc, base[(size_t)s * Dch]);
  float m = __fmul_rn(acc, 1.f / 256.f);   // /256 exact (pow2)
  float vacc = 0.f;
  for (int s = 0; s < 256; ++s){
    float d = __fsub_rn(base[(size_t)s * Dch], m);
    vacc = __fadd_rn(vacc, __fmul_rn(d, d));
  }
  int c = c0 + cl;
  mu[(size_t)c * Dch + ch]  = m;
  var[(size_t)c * Dch + ch] = __fmul_rn(vacc, 1.f / 256.f);
}

// fp32 BN + LIF scan (hidden layers): spike bitmasks, 64-thread blocks,
// software-pipelined chunk prefetch (8 independent loads in flight).
__global__ __launch_bounds__(64) void k_scan_spike_np(const float* __restrict__ A,
    const float* __restrict__ mu, const float* __restrict__ var,
    const float* __restrict__ g, const float* __restrict__ bt,
    float* __restrict__ vstate, unsigned long long* __restrict__ mask,
    int Dch, int c0, int nb){
  int ebn = Dch >> 6;
  int eb = blockIdx.x % ebn;
  int b  = blockIdx.x / ebn;
  int e  = (eb << 6) + threadIdx.x;
  float gg = g[e], bb = bt[e];
  float v = vstate[(size_t)b * Dch + e];
  float hbuf[8];
#pragma unroll
  for (int t = 0; t < 8; ++t)
    hbuf[t] = A[(size_t)(t * 32 + b) * Dch + e];
  for (int cl = 0; cl < nb; ++cl){
    int c = c0 + cl;
    float m  = mu[(size_t)c * Dch + e];
    float ve = __fadd_rn(var[(size_t)c * Dch + e], 1e-5f);
    float sq = (float)sqrt((double)ve);          // correctly-rounded fp32 sqrt
    float r  = (float)(1.0 / (double)sq);        // correctly-rounded fp32 div
    float hn[8];
    if (cl + 1 < nb){
#pragma unroll
      for (int t = 0; t < 8; ++t)
        hn[t] = A[(size_t)(((cl + 1) * 8 + t) * 32 + b) * Dch + e];
    } else {
#pragma unroll
      for (int t = 0; t < 8; ++t) hn[t] = 0.f;
    }
#pragma unroll
    for (int t = 0; t < 8; ++t){
      int sl = (cl * 8 + t) * 32 + b;
      float xn = __fadd_rn(__fmul_rn(__fmul_rn(gg, __fsub_rn(hbuf[t], m)), r), bb);
      v = __fadd_rn(v, __fmul_rn(__fsub_rn(xn, v), 0.5f));
      bool sp = (v >= 1.0f);                     // == (v-1>=0)
      unsigned long long bal = __ballot(sp);
      if (sp) v = 0.0f;
      if (threadIdx.x == 0) mask[(size_t)sl * 16 + eb] = bal;
    }
#pragma unroll
    for (int t = 0; t < 8; ++t) hbuf[t] = hn[t];
  }
  vstate[(size_t)b * Dch + e] = v;
}

// Sparse spike linear, Eigen order. Wave-cooperative list extraction:
// 16 lanes popcount their 64-bit mask word, __shfl exclusive prefix-scan,
// then parallel ascending writes into LDS. List order identical to the old
// serial scan -> single-accumulator ascending add chain preserved exactly.
// Consume loop: 8 weight rows in flight.
__global__ __launch_bounds__(256) void k_sparse_np(const unsigned long long* __restrict__ mask,
    const float* __restrict__ WT, const float* __restrict__ bias,
    float* __restrict__ C, int Dout){
  int tid = threadIdx.x;
  int lane = tid & 63;
  int wid = tid >> 6;
  int wps = Dout >> 8;            // waves per sample: 4 (1024) or 2 (512)
  int chgrp = wid % wps;
  int sgrp  = wid / wps;
  int spb   = 4 / wps;            // samples per block
  int s = blockIdx.x * spb + sgrp;
  int ch = (chgrp << 8) + (lane << 2);
  __shared__ unsigned short list[2][1024];
  __shared__ int nlist[2];

  if (chgrp == 0 && lane < 16){
    unsigned long long mw = mask[(size_t)s * 16 + lane];
    int cnt = __popcll(mw);
    int base = 0;
#pragma unroll
    for (int w = 0; w < 16; ++w){
      int cw = __shfl(cnt, w, 64);
      base += (w < lane) ? cw : 0;
    }
    int idx = base;
    while (mw){
      int bit = __ffsll(mw) - 1;
      mw &= mw - 1;
      list[sgrp][idx++] = (unsigned short)((lane << 6) + bit);
    }
    if (lane == 15) nlist[sgrp] = base + cnt;
  }
  __syncthreads();
  int n = nlist[sgrp];
  const unsigned short* il = list[sgrp];
  float a0 = 0.f, a1 = 0.f, a2 = 0.f, a3 = 0.f;
  int i = 0;
  for (; i + 8 <= n; i += 8){
    float4 wv[8];
#pragma unroll
    for (int u = 0; u < 8; ++u)
      wv[u] = *(const float4*)(WT + (size_t)il[i + u] * Dout + ch);
#pragma unroll
    for (int u = 0; u < 8; ++u){
      a0 = __fadd_rn(a0, wv[u].x); a1 = __fadd_rn(a1, wv[u].y);
      a2 = __fadd_rn(a2, wv[u].z); a3 = __fadd_rn(a3, wv[u].w);
    }
  }
  for (; i < n; ++i){
    int d = il[i];
    float4 wv = *(const float4*)(WT + (size_t)d * Dout + ch);
    a0 = __fadd_rn(a0, wv.x); a1 = __fadd_rn(a1, wv.y); a2 = __fadd_rn(a2, wv.z); a3 = __fadd_rn(a3, wv.w);
  }
  float4 bb = *(const float4*)(bias + ch);
  float4 o;
  o.x = __fadd_rn(a0, bb.x);
  o.y = __fadd_rn(a1, bb.y);
  o.z = __fadd_rn(a2, bb.z);
  o.w = __fadd_rn(a3, bb.w);
  *(float4*)(C + (size_t)s * Dout + ch) = o;
}

// Last layer: fp32 leaky integrator; sequential mean over 8 timesteps,
// /8 exact; float32 out. 64-thread blocks + chunk prefetch.
__global__ __launch_bounds__(64) void k_scan_last_np(const float* __restrict__ A,
    const float* __restrict__ mu, const float* __restrict__ var,
    const float* __restrict__ g, const float* __restrict__ bt,
    float* __restrict__ vstate, float* __restrict__ out, int c0, int nb){
  const int Dch = 512;
  int eb = blockIdx.x & 7;
  int b  = blockIdx.x >> 3;
  int e  = (eb << 6) + threadIdx.x;
  float gg = g[e], bb = bt[e];
  float v = vstate[(size_t)b * Dch + e];
  float hbuf[8];
#pragma unroll
  for (int t = 0; t < 8; ++t)
    hbuf[t] = A[(size_t)(t * 32 + b) * Dch + e];
  for (int cl = 0; cl < nb; ++cl){
    int c = c0 + cl;
    float m  = mu[(size_t)c * Dch + e];
    float ve = __fadd_rn(var[(size_t)c * Dch + e], 1e-5f);
    float sq = (float)sqrt((double)ve);
    float r  = (float)(1.0 / (double)sq);
    float hn[8];
    if (cl + 1 < nb){
#pragma unroll
      for (int t = 0; t < 8; ++t)
        hn[t] = A[(size_t)(((cl + 1) * 8 + t) * 32 + b) * Dch + e];
    } else {
#pragma unroll
      for (int t = 0; t < 8; ++t) hn[t] = 0.f;
    }
    float macc = 0.f;
#pragma unroll
    for (int t = 0; t < 8; ++t){
      float xn = __fadd_rn(__fmul_rn(__fmul_rn(gg, __fsub_rn(hbuf[t], m)), r), bb);
      v = __fadd_rn(v, __fmul_rn(__fsub_rn(xn, v), 0.5f));
      macc = __fadd_rn(macc, v);
    }
    out[((size_t)c * 32 + b) * 512 + e] = __fmul_rn(macc, 0.125f);
#pragma unroll
    for (int t = 0; t < 8; ++t) hbuf[t] = hn[t];
  }
  vstate[(size_t)b * Dch + e] = v;
}

static inline size_t al256(size_t x){ return (x + 255) & ~(size_t)255; }

extern "C" void kernel_launch(void* const* d_in, const int* in_sizes, int n_in,
                              void* d_out, int out_size, void* d_ws, size_t ws_size,
                              hipStream_t stream){
  (void)in_sizes; (void)n_in; (void)out_size;
  const float* x   = (const float*)d_in[0];
  const float* W0  = (const float*)d_in[1];
  const float* b0  = (const float*)d_in[2];
  const float* g0  = (const float*)d_in[3];
  const float* bt0 = (const float*)d_in[4];
  const float* W1  = (const float*)d_in[5];
  const float* b1  = (const float*)d_in[6];
  const float* g1  = (const float*)d_in[7];
  const float* bt1 = (const float*)d_in[8];
  const float* W2  = (const float*)d_in[9];
  const float* b2  = (const float*)d_in[10];
  const float* g2  = (const float*)d_in[11];
  const float* bt2 = (const float*)d_in[12];
  float* out = (float*)d_out;   // reference output dtype: float32

  char* p = (char*)d_ws;
  auto carve = [&](size_t bytes)->char*{ char* q = p; p += al256(bytes); return q; };
  float* W1T  = (float*)carve((size_t)1024 * 1024 * 4);   // [d=1024][e=1024]
  float* W2T  = (float*)carve((size_t)1024 * 512 * 4);    // [d=1024][e=512]
  float* mu0  = (float*)carve((size_t)128 * 1024 * 4);
  float* var0 = (float*)carve((size_t)128 * 1024 * 4);
  float* mu1  = (float*)carve((size_t)128 * 1024 * 4);
  float* var1 = (float*)carve((size_t)128 * 1024 * 4);
  float* mu2  = (float*)carve((size_t)128 * 512 * 4);
  float* var2 = (float*)carve((size_t)128 * 512 * 4);
  float* v0   = (float*)carve((size_t)32 * 1024 * 4);
  float* v1   = (float*)carve((size_t)32 * 1024 * 4);
  float* v2   = (float*)carve((size_t)32 * 512 * 4);
  size_t fixed_used = (size_t)(p - (char*)d_ws);

  auto need = [&](int nb)->size_t{
    return al256((size_t)nb * 256 * 1024 * 4)        // fp32 activation buffer
         + 2 * al256((size_t)nb * 256 * 16 * 8);     // mask0, mask1
  };
  int NB = 128;
  while (NB > 1 && fixed_used + need(NB) > ws_size) NB >>= 1;
  if (fixed_used + need(NB) > ws_size) return;

  float*              a_buf = (float*)carve((size_t)NB * 256 * 1024 * 4);
  unsigned long long* mask0 = (unsigned long long*)carve((size_t)NB * 256 * 16 * 8);
  unsigned long long* mask1 = (unsigned long long*)carve((size_t)NB * 256 * 16 * 8);

  // zero v-states (carved contiguously: 32*(1024+1024+512) floats)
  {
    int nz = 32 * (1024 + 1024 + 512);
    k_zero<<<dim3((nz + 255) / 256), dim3(256), 0, stream>>>((unsigned int*)v0, nz);
  }
  k_transpose<<<dim3(32, 32), dim3(32, 8), 0, stream>>>(W1, W1T, 1024, 1024);
  k_transpose<<<dim3(32, 16), dim3(32, 8), 0, stream>>>(W2, W2T, 512, 1024);

  int nblk = 128 / NB;
  for (int cb = 0; cb < nblk; ++cb){
    int c0 = cb * NB;
    int M = NB * 256;
    const float* xblk = x + (size_t)c0 * 256 * 512;

    // Layer 0 (Eigen-order FMA GEMM; n-tile-major grid for x L2 reuse)
    k_gemm_np<<<dim3(8, M / 128), dim3(256), 0, stream>>>(xblk, W0, b0, a_buf, M);
    k_stats_np<<<dim3(NB, 4), dim3(256), 0, stream>>>(a_buf, mu0, var0, 1024, c0);
    k_scan_spike_np<<<dim3(32 * 16), dim3(64), 0, stream>>>(a_buf, mu0, var0, g0, bt0, v0, mask0, 1024, c0, NB);

    // Layer 1 (sparse, ascending single-chain, batched loads)
    k_sparse_np<<<dim3(M), dim3(256), 0, stream>>>(mask0, W1T, b1, a_buf, 1024);
    k_stats_np<<<dim3(NB, 4), dim3(256), 0, stream>>>(a_buf, mu1, var1, 1024, c0);
    k_scan_spike_np<<<dim3(32 * 16), dim3(64), 0, stream>>>(a_buf, mu1, var1, g1, bt1, v1, mask1, 1024, c0, NB);

    // Layer 2 (sparse) + integrator output
    k_sparse_np<<<dim3(M / 2), dim3(256), 0, stream>>>(mask1, W2T, b2, a_buf, 512);
    k_stats_np<<<dim3(NB, 2), dim3(256), 0, stream>>>(a_buf, mu2, var2, 512, c0);
    k_scan_last_np<<<dim3(32 * 8), dim3(64), 0, stream>>>(a_buf, mu2, var2, g2, bt2, v2, out, c0, NB);
  }
}